// Round 4
// baseline (578.646 us; speedup 1.0000x reference)
//
#include <hip/hip_runtime.h>
#include <hip/hip_bf16.h>
#include <stdint.h>

// ---------------------------------------------------------------------------
// FiBiNet forward, MI355X (gfx950).  R6: fc0 GEMM -> true 8-phase schedule
// (4 quadrant-phases per K-tile, 2 barriers/phase, counted vmcnt, setprio).
// R5 post-mortem: one-barrier-per-tile == the known 2-phase plateau (693 TF
// measured vs m230's 682); MFMA pipe at ~90% of that structure's ceiling.
// T2 swizzle + T5 setprio only pay at 8-phase (regime-gate, m228d/m230).
// Staging: P0 issue A(t+1) DMA (pre-swizzled source, linear LDS dest);
// P1 vmcnt(4) drain B(t+1) regs -> cvt_pk -> swizzled ds_write; P2 issue
// B(t+2) fp32 global loads; P3 vmcnt(8) drain A(t+1) in MFMA shadow.
// ---------------------------------------------------------------------------

typedef __attribute__((ext_vector_type(4))) int   int4v;
typedef __attribute__((ext_vector_type(4))) unsigned uint4v;
typedef __attribute__((ext_vector_type(4))) float f32x4;

__device__ __forceinline__ unsigned short f32_bf16(float f) {
  unsigned u = __builtin_bit_cast(unsigned, f);
  u = (u + 0x7fffu + ((u >> 16) & 1u)) >> 16;   // RNE
  return (unsigned short)u;
}
__device__ __forceinline__ unsigned pk_bf16(float lo, float hi) {
  return (unsigned)f32_bf16(lo) | ((unsigned)f32_bf16(hi) << 16);
}
__device__ __forceinline__ unsigned cvt_pk(float lo, float hi) {
  unsigned r;
  asm("v_cvt_pk_bf16_f32 %0, %1, %2" : "=v"(r) : "v"(lo), "v"(hi));
  return r;
}

// ------------------------------- SE block ----------------------------------
__global__ __launch_bounds__(256) void se_kernel(
    const float* __restrict__ x, const float* __restrict__ w1,
    const float* __restrict__ w2, float* __restrict__ scale) {
  __shared__ float Z[32];
  __shared__ float A1[4];
  int b = blockIdx.x;
  int t = threadIdx.x;
  int f = t >> 3, sub = t & 7;
  const float4* xp = (const float4*)(x + (size_t)b * 2048 + f * 64 + sub * 8);
  float4 v0 = xp[0], v1 = xp[1];
  float s = v0.x + v0.y + v0.z + v0.w + v1.x + v1.y + v1.z + v1.w;
  s += __shfl_down(s, 4, 8);
  s += __shfl_down(s, 2, 8);
  s += __shfl_down(s, 1, 8);
  if (sub == 0) Z[f] = s * (1.0f / 64.0f);
  __syncthreads();
  if (t < 4) {
    float a = 0.f;
#pragma unroll
    for (int ff = 0; ff < 32; ++ff) a += Z[ff] * w1[t * 32 + ff];
    A1[t] = fmaxf(a, 0.f);
  }
  __syncthreads();
  if (t < 32) {
    float a = 0.f;
#pragma unroll
    for (int r = 0; r < 4; ++r) a += A1[r] * w2[t * 4 + r];
    scale[b * 32 + t] = 1.f / (1.f + expf(-a));
  }
}

// -------------------- per-field bilinear transforms ------------------------
__global__ __launch_bounds__(256) void t_kernel(
    const float* __restrict__ x, const float* __restrict__ W1,
    const float* __restrict__ W2, const float* __restrict__ scale,
    float* __restrict__ t1, float* __restrict__ t2) {
  __shared__ float Wl[64 * 65];
  __shared__ float xs[64 * 65];
  int f = blockIdx.x;
  int b0 = blockIdx.y * 64;
  int which = blockIdx.z;
  const float* W = (which ? W2 : W1) + (size_t)f * 4096;
  float* tout = which ? t2 : t1;
  int t = threadIdx.x;
#pragma unroll
  for (int it = 0; it < 16; ++it) {
    int idx = it * 256 + t;
    int o = idx >> 6, e = idx & 63;
    Wl[o * 65 + e] = W[idx];
  }
#pragma unroll
  for (int it = 0; it < 16; ++it) {
    int idx = it * 256 + t;
    int bl = idx >> 6, e = idx & 63;
    float v = x[(size_t)(b0 + bl) * 2048 + f * 64 + e];
    if (which) v *= scale[(b0 + bl) * 32 + f];
    xs[bl * 65 + e] = v;
  }
  __syncthreads();
  int o = t & 63, g = t >> 6;
  float sum[16];
#pragma unroll
  for (int r = 0; r < 16; ++r) sum[r] = 0.f;
#pragma unroll 4
  for (int e = 0; e < 64; ++e) {
    float wv = Wl[o * 65 + e];
#pragma unroll
    for (int r = 0; r < 16; ++r) sum[r] += xs[(g * 16 + r) * 65 + e] * wv;
  }
#pragma unroll
  for (int r = 0; r < 16; ++r)
    tout[(size_t)(b0 + g * 16 + r) * 1984 + f * 64 + o] = sum[r];
}

// ----------------------- pair feature materialization ----------------------
__global__ __launch_bounds__(256) void feat_kernel(
    const float* __restrict__ x, const float* __restrict__ t1,
    const float* __restrict__ t2, const float* __restrict__ scale,
    unsigned short* __restrict__ feat) {
  int gid = blockIdx.x * 256 + threadIdx.x;
  int b = gid / 7936;
  int rem = gid - b * 7936;
  int s = rem >> 3;
  int e0 = (rem & 7) * 8;
  int which = (s >= 496) ? 1 : 0;
  int p = s - (which ? 496 : 0);
  int i = (int)((63.0f - sqrtf((float)(3969 - 8 * p))) * 0.5f);
  while ((i * (63 - i)) / 2 > p) --i;
  while (((i + 1) * (62 - i)) / 2 <= p) ++i;
  int j = i + 1 + (p - (i * (63 - i)) / 2);
  const float* tp = (which ? t2 : t1) + (size_t)b * 1984 + i * 64 + e0;
  const float* xp = x + (size_t)b * 2048 + j * 64 + e0;
  float sc = which ? scale[b * 32 + j] : 1.0f;
  float4 ta = *(const float4*)tp, tb = *(const float4*)(tp + 4);
  float4 xa = *(const float4*)xp, xb = *(const float4*)(xp + 4);
  uint4v o;
  o.x = pk_bf16(ta.x * xa.x * sc, ta.y * xa.y * sc);
  o.y = pk_bf16(ta.z * xa.z * sc, ta.w * xa.w * sc);
  o.z = pk_bf16(tb.x * xb.x * sc, tb.y * xb.y * sc);
  o.w = pk_bf16(tb.z * xb.z * sc, tb.w * xb.w * sc);
  *(uint4v*)(feat + (size_t)b * 63488 + s * 64 + e0) = o;
}

// ------------------------------- MFMA GEMM ---------------------------------
__device__ __forceinline__ void mfma_bf16(f32x4& d, int4v a, int4v b) {
  asm volatile("v_mfma_f32_16x16x32_bf16 %0, %1, %2, %0"
               : "+v"(d) : "v"(a), "v"(b));
}

// ---- fc0 pipeline GEMM: 256x256 tile, BK=64, 512 thr (8 waves 2Mx4N).
#define FBM 256
#define FBN 256
#define FBK 64

__device__ __forceinline__ void fc0_read_av(
    const unsigned short* sAb, int kk, int wr, int l15, int l4, int4v (&av)[8]) {
#pragma unroll
  for (int i = 0; i < 8; ++i) {
    int ar = wr + i * 16 + l15;
    av[i] = *(const int4v*)&sAb[(ar * 8 + ((kk * 4 + l4) ^ (ar & 7))) * 8];
  }
}
__device__ __forceinline__ void fc0_read_bv(
    const unsigned short* sBb, int kk, int j0, int wc, int l15, int l4,
    int4v (&bv)[2]) {
#pragma unroll
  for (int j = 0; j < 2; ++j) {
    int br = wc + (j0 + j) * 16 + l15;
    bv[j] = *(const int4v*)&sBb[(br * 8 + ((kk * 4 + l4) ^ (br & 7))) * 8];
  }
}
__device__ __forceinline__ void fc0_mfma8x2(
    f32x4 (&acc)[8][4], int j0, int4v (&av)[8], int4v (&bv)[2]) {
  __builtin_amdgcn_s_setprio(1);
#pragma unroll
  for (int i = 0; i < 8; ++i)
#pragma unroll
    for (int j = 0; j < 2; ++j) mfma_bf16(acc[i][j0 + j], av[i], bv[j]);
  __builtin_amdgcn_s_setprio(0);
}

__global__ __launch_bounds__(512, 2) void gemm_fc0(
    const unsigned short* __restrict__ A, const float* __restrict__ Bp,
    float* __restrict__ Cp, int M, int N, int K, int kz) {
  __shared__ unsigned short sA[2][FBM * FBK];  // 2 x 32 KB bf16
  __shared__ unsigned short sB[2][FBN * FBK];  // 2 x 32 KB bf16
  int tid = threadIdx.x;
  int lane = tid & 63;
  int wave = tid >> 6;
  // bid = s + 64*m, s = n + 4*z : the 4 m-blocks of one (n,z) share an XCD
  int bid = blockIdx.x;
  int m0 = (bid >> 6) << 8;
  int s  = bid & 63;
  int n0 = (s & 3) << 8;
  int z  = s >> 2;                 // 0..15
  int wr = (wave >> 2) * 128, wc = (wave & 3) * 64;
  int l15 = lane & 15, l4 = lane >> 4;
  int kbase = z * kz;
  int nt = kz / FBK;               // 62

  f32x4 acc[8][4];
#pragma unroll
  for (int i = 0; i < 8; ++i)
#pragma unroll
    for (int j = 0; j < 4; ++j) acc[i][j] = (f32x4){0.f, 0.f, 0.f, 0.f};

  // staging maps: 2048 chunks of 16B out per operand; 4 chunks/thread
  unsigned aOff[4]; int aDst[4];
  unsigned bOff[4]; int bDst[4];
#pragma unroll
  for (int it = 0; it < 4; ++it) {
    int c = it * 512 + tid;
    int r = c >> 3, l = c & 7;
    aOff[it] = (unsigned)(m0 + r) * (unsigned)K + (unsigned)((l ^ (r & 7)) << 3);
    aDst[it] = c * 8;                       // shorts (16B chunks, linear)
    bOff[it] = (unsigned)(n0 + r) * (unsigned)K + (unsigned)(l << 3);
    bDst[it] = (r * 8 + (l ^ (r & 7))) * 8; // shorts (swizzled dest)
  }

  unsigned short* sAc = &sA[0][0];
  unsigned short* sAn = &sA[1][0];
  unsigned short* sBc = &sB[0][0];
  unsigned short* sBn = &sB[1][0];

#define FC0_STAGE_A(dstp, kt)                                                  \
  _Pragma("unroll") for (int it = 0; it < 4; ++it) {                           \
    __builtin_amdgcn_global_load_lds(                                          \
        (const __attribute__((address_space(1))) void*)(A + aOff[it] + (kt)),  \
        (__attribute__((address_space(3))) void*)((dstp) + aDst[it]), 16, 0, 0); \
  }
#define FC0_LOAD_B(kt)                                                         \
  _Pragma("unroll") for (int it = 0; it < 4; ++it) {                           \
    const float* gp = Bp + bOff[it] + (kt);                                    \
    bst[2 * it]     = *(const float4*)gp;                                      \
    bst[2 * it + 1] = *(const float4*)(gp + 4);                                \
  }
#define FC0_WRITE_B(dstp)                                                      \
  _Pragma("unroll") for (int it = 0; it < 4; ++it) {                           \
    uint4v q;                                                                  \
    q.x = cvt_pk(bst[2 * it].x, bst[2 * it].y);                                \
    q.y = cvt_pk(bst[2 * it].z, bst[2 * it].w);                                \
    q.z = cvt_pk(bst[2 * it + 1].x, bst[2 * it + 1].y);                        \
    q.w = cvt_pk(bst[2 * it + 1].z, bst[2 * it + 1].w);                        \
    *(uint4v*)((dstp) + bDst[it]) = q;                                         \
  }
#define BAR()  __builtin_amdgcn_s_barrier()
#define LGKM0() asm volatile("s_waitcnt lgkmcnt(0)" ::: "memory")

// One K-tile as 4 quadrant-phases.  DO_SA: stage A(t+1)+write B(t+1);
// DO_LB: issue B(t+2) loads; WAITS: vmcnt immediate for the A(t+1) drain.
#define FC0_TILE(KT1, KT2, DO_SA, DO_LB, WAITS)                                \
  {                                                                            \
    /* P0: stage A(t+1); compute kk0, j0-1 */                                  \
    if (DO_SA) { FC0_STAGE_A(sAn, KT1) }                                       \
    fc0_read_av(sAc, 0, wr, l15, l4, av);                                      \
    fc0_read_bv(sBc, 0, 0, wc, l15, l4, bv);                                   \
    BAR(); LGKM0();                                                            \
    fc0_mfma8x2(acc, 0, av, bv);                                               \
    BAR();                                                                     \
    /* P1: drain B(t+1) regs (counted), publish sB[nxt]; kk0, j2-3 */          \
    if (DO_SA) {                                                               \
      asm volatile("s_waitcnt vmcnt(4)" ::: "memory");                         \
      FC0_WRITE_B(sBn)                                                         \
    }                                                                          \
    fc0_read_bv(sBc, 0, 2, wc, l15, l4, bv);                                   \
    BAR(); LGKM0();                                                            \
    fc0_mfma8x2(acc, 2, av, bv);                                               \
    BAR();                                                                     \
    /* P2: issue B(t+2) global loads; kk1, j0-1 */                             \
    if (DO_LB) { FC0_LOAD_B(KT2) }                                             \
    fc0_read_av(sAc, 1, wr, l15, l4, av);                                      \
    fc0_read_bv(sBc, 1, 0, wc, l15, l4, bv);                                   \
    BAR(); LGKM0();                                                            \
    fc0_mfma8x2(acc, 0, av, bv);                                               \
    BAR();                                                                     \
    /* P3: kk1, j2-3; drain A(t+1) DMA in MFMA shadow */                       \
    fc0_read_bv(sBc, 1, 2, wc, l15, l4, bv);                                   \
    BAR(); LGKM0();                                                            \
    fc0_mfma8x2(acc, 2, av, bv);                                               \
    asm volatile("s_waitcnt " WAITS ::: "memory");                             \
    BAR();                                                                     \
  }
#define FC0_SWAP()                                                             \
  { unsigned short* tp;                                                        \
    tp = sAc; sAc = sAn; sAn = tp;                                             \
    tp = sBc; sBc = sBn; sBn = tp; }

  float4 bst[8];
  int4v av[8], bv[2];
  // ---- prologue: B(0)->regs->sB0; A(0) DMA->sA0; B(1)->regs ----
  FC0_LOAD_B(kbase)                                        // B0 x8
  FC0_STAGE_A(sAc, kbase)                                  // A0 x4
  asm volatile("s_waitcnt vmcnt(4)" ::: "memory");         // B0 regs ready
  FC0_WRITE_B(sBc)
  FC0_LOAD_B(kbase + FBK)                                  // B1 x8
  asm volatile("s_waitcnt vmcnt(8) lgkmcnt(0)" ::: "memory");  // A0 done
  BAR();

  // main: t = 0 .. nt-3 (all guards true, vmcnt never 0)
#pragma unroll 2
  for (int t = 0; t < nt - 2; ++t) {
    FC0_TILE(kbase + (t + 1) * FBK, kbase + (t + 2) * FBK, 1, 1, "vmcnt(8)")
    FC0_SWAP()
  }
  // t = nt-2: stage/publish last tile, no B(t+2); drain A fully
  FC0_TILE(kbase + (nt - 1) * FBK, 0, 1, 0, "vmcnt(0)")
  FC0_SWAP()
  // t = nt-1: pure compute
  FC0_TILE(0, 0, 0, 0, "vmcnt(0)")

#undef FC0_TILE
#undef FC0_SWAP
#undef FC0_STAGE_A
#undef FC0_LOAD_B
#undef FC0_WRITE_B
#undef BAR
#undef LGKM0

  asm volatile("s_nop 7\n\ts_nop 7\n\ts_nop 7" ::: "memory");
  float* cp = Cp + (size_t)z * M * N;
#pragma unroll
  for (int i = 0; i < 8; ++i) {
    int rbase = m0 + wr + i * 16 + l4 * 4;
#pragma unroll
    for (int j = 0; j < 4; ++j) {
      int cc = n0 + wc + j * 16 + l15;
#pragma unroll
      for (int r = 0; r < 4; ++r)
        cp[(size_t)(rbase + r) * N + cc] = acc[i][j][r];
    }
  }
}

// ---- legacy GEMM (kept for fc1): 256x128 block tile, 4 waves, 2-barrier ----
#define BM 256
#define BN 128
#define BK 64

__global__ __launch_bounds__(256, 2) void gemm_bt(
    const unsigned short* __restrict__ A, const float* __restrict__ B,
    float* __restrict__ Cp, int M, int N, int K, int kz) {
  __shared__ unsigned short sA[BM * BK];   // 32 KB
  __shared__ unsigned short sB[BN * BK];   // 16 KB
  int tid = threadIdx.x;
  int lane = tid & 63, wave = tid >> 6;
  int n0 = blockIdx.x * BN, m0 = blockIdx.y * BM;
  int z = blockIdx.z;
  int wr = (wave >> 1) * 128, wc = (wave & 1) * 64;
  int l15 = lane & 15, l4 = lane >> 4;
  f32x4 acc[8][4];
#pragma unroll
  for (int i = 0; i < 8; ++i)
#pragma unroll
    for (int j = 0; j < 4; ++j) acc[i][j] = (f32x4){0.f, 0.f, 0.f, 0.f};

  int kend = z * kz + kz;
  for (int kt = z * kz; kt < kend; kt += BK) {
#pragma unroll
    for (int it = 0; it < 8; ++it) {
      int c = it * 256 + tid;
      int r = c >> 3, p = c & 7;
      int gcol = (p ^ (r & 7)) * 8;
      const unsigned short* gp = A + (size_t)(m0 + r) * K + kt + gcol;
      __builtin_amdgcn_global_load_lds(
          (const __attribute__((address_space(1))) void*)gp,
          (__attribute__((address_space(3))) void*)(&sA[c * 8]), 16, 0, 0);
    }
#pragma unroll
    for (int it = 0; it < 4; ++it) {
      int c = it * 256 + tid;
      int r = c >> 3, l = c & 7;
      const float* gp = B + (size_t)(n0 + r) * K + kt + l * 8;
      float4 f0 = *(const float4*)gp;
      float4 f1 = *(const float4*)(gp + 4);
      uint4v q;
      q.x = pk_bf16(f0.x, f0.y); q.y = pk_bf16(f0.z, f0.w);
      q.z = pk_bf16(f1.x, f1.y); q.w = pk_bf16(f1.z, f1.w);
      int p = l ^ (r & 7);
      *(uint4v*)(&sB[(r * 8 + p) * 8]) = q;
    }
    __syncthreads();
#pragma unroll
    for (int kk = 0; kk < 2; ++kk) {
      int lc = kk * 4 + l4;
      int4v av[8], bv[4];
#pragma unroll
      for (int i = 0; i < 8; ++i) {
        int ar = wr + i * 16 + l15;
        av[i] = *(const int4v*)&sA[(ar * 8 + (lc ^ (ar & 7))) * 8];
      }
#pragma unroll
      for (int j = 0; j < 4; ++j) {
        int br = wc + j * 16 + l15;
        bv[j] = *(const int4v*)&sB[(br * 8 + (lc ^ (br & 7))) * 8];
      }
#pragma unroll
      for (int i = 0; i < 8; ++i)
#pragma unroll
        for (int j = 0; j < 4; ++j) mfma_bf16(acc[i][j], av[i], bv[j]);
    }
    __syncthreads();
  }
  asm volatile("s_nop 7\n\ts_nop 7\n\ts_nop 7" ::: "memory");
  float* cp = Cp + (size_t)z * M * N;
#pragma unroll
  for (int i = 0; i < 8; ++i) {
    int rbase = m0 + wr + i * 16 + l4 * 4;
#pragma unroll
    for (int j = 0; j < 4; ++j) {
      int cc = n0 + wc + j * 16 + l15;
#pragma unroll
      for (int r = 0; r < 4; ++r)
        cp[(size_t)(rbase + r) * N + cc] = acc[i][j][r];
    }
  }
}

// --------------------- splitK reduce + bias + relu -------------------------
__global__ __launch_bounds__(256) void reduce_bias_act(
    const float* __restrict__ parts, const float* __restrict__ bias,
    int MN, int nmask, int nz, unsigned short* __restrict__ out_bf,
    float* __restrict__ out_f) {
  int idx = blockIdx.x * 256 + threadIdx.x;
  if (idx >= MN) return;
  float s = 0.f;
  for (int z = 0; z < nz; ++z) s += parts[(size_t)z * MN + idx];
  s += bias[idx & nmask];
  s = fmaxf(s, 0.f);
  if (out_bf) out_bf[idx] = f32_bf16(s);
  else out_f[idx] = s;
}

// ------------------------------ fc2 + sigmoid ------------------------------
__global__ __launch_bounds__(256) void fc2_kernel(
    const float* __restrict__ h2, const float* __restrict__ w,
    const float* __restrict__ b, float* __restrict__ out) {
  int wave = threadIdx.x >> 6, lane = threadIdx.x & 63;
  int row = blockIdx.x * 4 + wave;
  const float4* hp = (const float4*)(h2 + (size_t)row * 512);
  const float4* wp = (const float4*)w;
  int i0 = lane * 2;
  float4 a0 = hp[i0], a1 = hp[i0 + 1];
  float4 w0 = wp[i0], w1 = wp[i0 + 1];
  float s = a0.x * w0.x + a0.y * w0.y + a0.z * w0.z + a0.w * w0.w +
            a1.x * w1.x + a1.y * w1.y + a1.z * w1.z + a1.w * w1.w;
#pragma unroll
  for (int off = 32; off > 0; off >>= 1) s += __shfl_down(s, off);
  if (lane == 0) out[row] = 1.f / (1.f + expf(-(s + b[0])));
}

// ---------------------------------------------------------------------------
extern "C" void kernel_launch(void* const* d_in, const int* in_sizes, int n_in,
                              void* d_out, int out_size, void* d_ws, size_t ws_size,
                              hipStream_t stream) {
  const float* x     = (const float*)d_in[0];
  const float* Wb1   = (const float*)d_in[1];
  const float* Wb2   = (const float*)d_in[2];
  const float* se_w1 = (const float*)d_in[3];
  const float* se_w2 = (const float*)d_in[4];
  const float* fc0_w = (const float*)d_in[5];
  const float* fc0_b = (const float*)d_in[6];
  const float* fc1_w = (const float*)d_in[7];
  const float* fc1_b = (const float*)d_in[8];
  const float* fc2_w = (const float*)d_in[9];
  const float* fc2_b = (const float*)d_in[10];
  (void)in_sizes; (void)n_in; (void)out_size; (void)ws_size;

  char* ws = (char*)d_ws;
  float*          scale = (float*)(ws + 0);                   //  128 KB
  float*          t1    = (float*)(ws + 131072);              //  7.75 MB
  float*          t2    = (float*)(ws + 8257536);             //  7.75 MB
  unsigned short* feat  = (unsigned short*)(ws + 16384000);   //  124 MB bf16
  float*          hp    = (float*)(ws + 146407424);           //  64 MB partials
  unsigned short* h1b   = (unsigned short*)(ws + 213516288);  //  2 MB bf16
  float*          h2    = (float*)(ws + 215613440);           //  2 MB
  float*          out   = (float*)d_out;

  se_kernel<<<1024, 256, 0, stream>>>(x, se_w1, se_w2, scale);
  t_kernel<<<dim3(31, 16, 2), 256, 0, stream>>>(x, Wb1, Wb2, scale, t1, t2);
  feat_kernel<<<31744, 256, 0, stream>>>(x, t1, t2, scale, feat);
  // fc0: M=1024 N=1024 K=63488, splitK=16 (kz=3968 = 62 k-tiles), 256 blocks
  gemm_fc0<<<256, 512, 0, stream>>>(feat, fc0_w, hp, 1024, 1024, 63488, 3968);
  reduce_bias_act<<<4096, 256, 0, stream>>>(hp, fc0_b, 1024 * 1024, 1023, 16, h1b, nullptr);
  // fc1: M=1024 N=512 K=1024, splitK=16 (kz=64)
  gemm_bt<<<dim3(4, 4, 16), 256, 0, stream>>>(h1b, fc1_w, hp, 1024, 512, 1024, 64);
  reduce_bias_act<<<2048, 256, 0, stream>>>(hp, fc1_b, 1024 * 512, 511, 16, nullptr, h2);
  fc2_kernel<<<256, 256, 0, stream>>>(h2, fc2_w, fc2_b, out);
}